// Round 13
// baseline (333.749 us; speedup 1.0000x reference)
//
#include <hip/hip_runtime.h>
#include <hip/hip_bf16.h>
#include <math.h>

#define BB 8
#define NN 2048
#define TN 4096
#define DD 64

typedef __attribute__((ext_vector_type(8))) short short8;
typedef __attribute__((ext_vector_type(4))) float f32x4;
typedef __attribute__((ext_vector_type(4))) unsigned int u32x4;

__device__ __forceinline__ unsigned short f2bf(float f) {
    union { float f; unsigned int i; } v; v.f = f;
    unsigned int r = v.i + 0x7FFF + ((v.i >> 16) & 1);   // RNE
    return (unsigned short)(r >> 16);
}
__device__ __forceinline__ float bf2f(unsigned short u) {
    union { unsigned int i; float f; } v; v.i = ((unsigned int)u) << 16; return v.f;
}

// K1: Wh = concat(ht,h) @ W (f32); s1 = Wh@a1, s2 = Wh@a2; exp tables.
__global__ void k1_wh(const float* __restrict__ h,
                      const float* __restrict__ ht,
                      const float* __restrict__ W,
                      const float* __restrict__ a1,
                      const float* __restrict__ a2,
                      float* __restrict__ Wh,
                      float* __restrict__ E1p, float* __restrict__ E1n,
                      float* __restrict__ E2p, float* __restrict__ E2n,
                      float* __restrict__ E1i) {
    int tid = threadIdx.x;
    int w = tid >> 6, l = tid & 63;
    int rowglob = blockIdx.x * 4 + w;          // b*TN + m
    int b = rowglob >> 12;
    int m = rowglob & (TN - 1);
    const float* src = (m < NN) ? (ht + ((size_t)b * NN + m) * DD)
                                : (h  + ((size_t)b * NN + (m - NN)) * DD);
    const f32x4* src4 = reinterpret_cast<const f32x4*>(src);
    float c0 = 0.f, c1 = 0.f, c2 = 0.f, c3 = 0.f;
    #pragma unroll
    for (int k = 0; k < 16; ++k) {
        f32x4 s = src4[k];                      // wave-uniform 16B broadcast
        c0 += s[0] * W[(k * 4 + 0) * 64 + l];
        c1 += s[1] * W[(k * 4 + 1) * 64 + l];
        c2 += s[2] * W[(k * 4 + 2) * 64 + l];
        c3 += s[3] * W[(k * 4 + 3) * 64 + l];
    }
    float acc = (c0 + c1) + (c2 + c3);
    Wh[((size_t)b * TN + m) * DD + l] = acc;
    float r1 = acc * a1[l];
    float r2 = acc * a2[l];
    #pragma unroll
    for (int off = 32; off > 0; off >>= 1) {
        r1 += __shfl_xor(r1, off, 64);
        r2 += __shfl_xor(r2, off, 64);
    }
    if (l == 0) {
        size_t o = (size_t)b * TN + m;
        float pp = __expf(r1), pn = __expf(0.2f * r1);
        E1p[o] = pp;
        E1n[o] = pn;
        int sp = (b < 4) ? b       : 8 + (b - 4);
        int sn = (b < 4) ? 4 + b   : 12 + (b - 4);
        E1i[(size_t)m * 16 + sp] = pp;
        E1i[(size_t)m * 16 + sn] = pn;
        E2p[o] = __expf(r2);
        E2n[o] = __expf(0.2f * r2);
    }
}

// K2 (fused mask+stats): one streaming pass over adj (64 MB).
__global__ __launch_bounds__(256) void k2_mask_stats(
    const float* __restrict__ adj,
    const float* __restrict__ E1i,
    const float* __restrict__ E2p, const float* __restrict__ E2n,
    unsigned long long* __restrict__ rowmask,
    float* __restrict__ Spart) {
    int tid = threadIdx.x;
    int w = tid >> 6, l = tid & 63;
    int j = blockIdx.x * 256 + tid;
    int i0 = blockIdx.y * 64;
    f32x4 e2p0, e2p1, e2n0, e2n1;
    #pragma unroll
    for (int b = 0; b < 4; ++b) {
        e2p0[b] = E2p[(size_t)b * TN + j];
        e2n0[b] = E2n[(size_t)b * TN + j];
        e2p1[b] = E2p[(size_t)(b + 4) * TN + j];
        e2n1[b] = E2n[(size_t)(b + 4) * TN + j];
    }
    f32x4 acc0 = {0.f, 0.f, 0.f, 0.f}, acc1 = {0.f, 0.f, 0.f, 0.f};
    const f32x4* e1 = reinterpret_cast<const f32x4*>(E1i + (size_t)i0 * 16);
    #pragma unroll 4
    for (int ii = 0; ii < 64; ++ii) {
        float av = adj[(size_t)(i0 + ii) * TN + j];     // coalesced 256B/wave
        unsigned long long bal = __ballot(av != 0.f);
        if (l == 0)
            rowmask[(size_t)(i0 + ii) * 64 + blockIdx.x * 4 + w] = bal;
        f32x4 P0 = e1[ii * 4 + 0];                      // wave-uniform loads
        f32x4 N0 = e1[ii * 4 + 1];
        f32x4 P1 = e1[ii * 4 + 2];
        f32x4 N1 = e1[ii * 4 + 3];
        f32x4 v0 = __builtin_elementwise_max(P0 * e2p0, N0 * e2n0);
        f32x4 v1 = __builtin_elementwise_max(P1 * e2p1, N1 * e2n1);
        acc0 += v0 * av;                                 // av in {0,1}: exact mask
        acc1 += v1 * av;
    }
    #pragma unroll
    for (int b = 0; b < 4; ++b) {
        Spart[((size_t)blockIdx.y * 8 + b) * TN + j]     = acc0[b];
        Spart[((size_t)blockIdx.y * 8 + b + 4) * TN + j] = acc1[b];
    }
}

// K3: reduce Spart -> 1/S, then Whn_t[b][d][j] = Wh[b][j][d]/S[b][j] (bf16 T)
__global__ __launch_bounds__(256) void k3_whn(
    const float* __restrict__ Wh,
    const float* __restrict__ Spart,
    unsigned short* __restrict__ Wt) {
    __shared__ float tile[64][65];
    __shared__ float ps[4][64];
    __shared__ float rs[64];
    int b = blockIdx.y;
    int j0 = blockIdx.x * 64;
    int tid = threadIdx.x;
    int jj = tid & 63, part = tid >> 6;
    float s = 0.f;
    #pragma unroll
    for (int k = 0; k < 16; ++k) {
        int is = part * 16 + k;
        s += Spart[((size_t)is * 8 + b) * TN + j0 + jj];
    }
    ps[part][jj] = s;
    __syncthreads();
    if (tid < 64) rs[tid] = 1.0f / (ps[0][tid] + ps[1][tid] + ps[2][tid] + ps[3][tid]);
    for (int e = tid; e < 4096; e += 256) {
        int jt = e >> 6, d = e & 63;
        tile[jt][d] = Wh[((size_t)b * TN + j0 + jt) * DD + d];
    }
    __syncthreads();
    for (int e = tid; e < 512; e += 256) {
        int d = e >> 3, jg = e & 7;
        union { unsigned short u[8]; short8 s8; } pk;
        #pragma unroll
        for (int k = 0; k < 8; ++k) {
            int jt = jg * 8 + k;
            pk.u[k] = f2bf(tile[jt][d] * rs[jt]);
        }
        *reinterpret_cast<short8*>(Wt + ((size_t)b * DD + d) * TN + j0 + jg * 8) = pk.s8;
    }
}

// K4: hp partials, P on the fly in MFMA A-layout. NO LDS, NO BARRIERS:
// B-fragments loaded directly from L2-resident Wt (16 B contiguous per lane,
// wave touches 16 full 64B lines). Waves fully independent -> VALU/vmem/MFMA
// overlap across 32 waves/CU. 256 thr (4 waves), i-tile 64, js=4, grid 2048.
__global__ __launch_bounds__(256) void k4_pv(
    const unsigned int* __restrict__ rowmask32,
    const float* __restrict__ E1p, const float* __restrict__ E1n,
    const float* __restrict__ E2p, const float* __restrict__ E2n,
    const unsigned short* __restrict__ Wt,
    unsigned short* __restrict__ hpq) {
    int bx = blockIdx.x;
    int b  = bx & 7;                 // XCD round-robin
    int js = (bx >> 3) & 3;
    int it = bx >> 5;                // i-tile index 0..63
    int i0 = it * 64;
    int tid = threadIdx.x;
    int w = tid >> 6, l = tid & 63;
    int m = l & 15, q = l >> 4;
    int irow = i0 + w * 16 + m;
    float e1p_v = E1p[(size_t)b * TN + irow];
    float e1n_v = E1n[(size_t)b * TN + irow];
    const float* e2pb = E2p + (size_t)b * TN;
    const float* e2nb = E2n + (size_t)b * TN;
    const unsigned short* wtb = Wt + (size_t)b * DD * TN + m * TN;  // row dt*16+m
    const unsigned int* mrow = rowmask32 + (size_t)irow * 128;
    const int jbase = js * 1024;

    f32x4 acc[4];
    #pragma unroll
    for (int dt = 0; dt < 4; ++dt) acc[dt] = (f32x4){0.f, 0.f, 0.f, 0.f};

    for (int jt = 0; jt < 8; ++jt) {
        int j0 = jbase + jt * 128;
        u32x4 m4 = *reinterpret_cast<const u32x4*>(mrow + (j0 >> 5));
        #pragma unroll
        for (int t = 0; t < 4; ++t) {
            int jb = j0 + t * 32 + q * 8;
            // B-fragments straight from L2 (no LDS round-trip)
            short8 bf0 = *reinterpret_cast<const short8*>(wtb + (size_t)0 * 16 * TN + jb);
            short8 bf1 = *reinterpret_cast<const short8*>(wtb + (size_t)1 * 16 * TN + jb);
            short8 bf2 = *reinterpret_cast<const short8*>(wtb + (size_t)2 * 16 * TN + jb);
            short8 bf3 = *reinterpret_cast<const short8*>(wtb + (size_t)3 * 16 * TN + jb);
            unsigned int bytev = (m4[t] >> (q * 8)) & 0xFFu;
            f32x4 p20 = *reinterpret_cast<const f32x4*>(e2pb + jb);
            f32x4 p21 = *reinterpret_cast<const f32x4*>(e2pb + jb + 4);
            f32x4 n20 = *reinterpret_cast<const f32x4*>(e2nb + jb);
            f32x4 n21 = *reinterpret_cast<const f32x4*>(e2nb + jb + 4);
            f32x4 v0 = __builtin_elementwise_max(p20 * e1p_v, n20 * e1n_v);
            f32x4 v1 = __builtin_elementwise_max(p21 * e1p_v, n21 * e1n_v);
            union { f32x4 f; u32x4 u; } uv0, uv1;
            uv0.f = v0; uv1.f = v1;
            u32x4 mk0, mk1;
            #pragma unroll
            for (int c = 0; c < 4; ++c) {
                mk0[c] = (unsigned int)((int)(bytev << (31 - c)) >> 31);
                mk1[c] = (unsigned int)((int)(bytev << (27 - c)) >> 31);
            }
            uv0.u &= mk0; uv1.u &= mk1;
            union { unsigned int u[4]; short8 s8; } af;
            __hip_bfloat162 hb0 = __float22bfloat162_rn(make_float2(uv0.f[0], uv0.f[1]));
            __hip_bfloat162 hb1 = __float22bfloat162_rn(make_float2(uv0.f[2], uv0.f[3]));
            __hip_bfloat162 hb2 = __float22bfloat162_rn(make_float2(uv1.f[0], uv1.f[1]));
            __hip_bfloat162 hb3 = __float22bfloat162_rn(make_float2(uv1.f[2], uv1.f[3]));
            af.u[0] = *reinterpret_cast<unsigned int*>(&hb0);
            af.u[1] = *reinterpret_cast<unsigned int*>(&hb1);
            af.u[2] = *reinterpret_cast<unsigned int*>(&hb2);
            af.u[3] = *reinterpret_cast<unsigned int*>(&hb3);
            acc[0] = __builtin_amdgcn_mfma_f32_16x16x32_bf16(af.s8, bf0, acc[0], 0, 0, 0);
            acc[1] = __builtin_amdgcn_mfma_f32_16x16x32_bf16(af.s8, bf1, acc[1], 0, 0, 0);
            acc[2] = __builtin_amdgcn_mfma_f32_16x16x32_bf16(af.s8, bf2, acc[2], 0, 0, 0);
            acc[3] = __builtin_amdgcn_mfma_f32_16x16x32_bf16(af.s8, bf3, acc[3], 0, 0, 0);
        }
    }

    // Epilogue: lane-native layout. element (js,b,it,w,lane,k) with k=dt*4+r.
    union { unsigned int u[8]; u32x4 v[2]; } pk;
    #pragma unroll
    for (int dt = 0; dt < 4; ++dt) {
        __hip_bfloat162 p0 = __float22bfloat162_rn(make_float2(acc[dt][0], acc[dt][1]));
        __hip_bfloat162 p1 = __float22bfloat162_rn(make_float2(acc[dt][2], acc[dt][3]));
        pk.u[dt * 2 + 0] = *reinterpret_cast<unsigned int*>(&p0);
        pk.u[dt * 2 + 1] = *reinterpret_cast<unsigned int*>(&p1);
    }
    unsigned short* hp = hpq +
        (((((size_t)js * 8 + b) * 64 + it) * 4 + w) * 64 + l) * 16;
    *reinterpret_cast<u32x4*>(hp)     = pk.v[0];
    *reinterpret_cast<u32x4*>(hp + 8) = pk.v[1];
}

// K5: out = elu(sum_js hp[js]) with concat remap + layout unpermute; f32 store.
__global__ void k5_epi(const unsigned short* __restrict__ hpq,
                       float* __restrict__ out) {
    int t = blockIdx.x * 256 + threadIdx.x;       // < 524288
    int d4 = t & 31;
    int n = (t >> 5) & 2047;
    int b = t >> 16;
    int g, sd;
    if (d4 < 16) { g = n;        sd = d4 * 4; }
    else         { g = n + NN;   sd = (d4 - 16) * 4; }
    int it = g >> 6, w = (g >> 4) & 3, q = (g >> 2) & 3, r = g & 3;
    int dt = sd >> 4, m0 = sd & 15;
    const size_t JSTR = (size_t)8 * 64 * 4 * 64 * 16;   // 2,097,152 ushorts / js
    size_t base = ((((size_t)b * 64 + it) * 4 + w) * 64 + q * 16) * 16 + dt * 4 + r;
    f32x4 s = {0.f, 0.f, 0.f, 0.f};
    #pragma unroll
    for (int js = 0; js < 4; ++js) {
        const unsigned short* p = hpq + js * JSTR + base;
        #pragma unroll
        for (int c = 0; c < 4; ++c) s[c] += bf2f(p[(size_t)(m0 + c) * 16]);
    }
    f32x4 rr;
    #pragma unroll
    for (int c = 0; c < 4; ++c) rr[c] = (s[c] > 0.f) ? s[c] : expm1f(s[c]);
    *reinterpret_cast<f32x4*>(out + ((size_t)b * NN + n) * 128 + d4 * 4) = rr;
}

extern "C" void kernel_launch(void* const* d_in, const int* in_sizes, int n_in,
                              void* d_out, int out_size, void* d_ws, size_t ws_size,
                              hipStream_t stream) {
    const float* h   = (const float*)d_in[0];
    const float* ht  = (const float*)d_in[1];
    const float* W   = (const float*)d_in[2];
    const float* a1  = (const float*)d_in[3];
    const float* a2  = (const float*)d_in[4];
    const float* adj = (const float*)d_in[5];
    float* out = (float*)d_out;

    char* ws = (char*)d_ws;
    float* Wh          = (float*)(ws);                       // 8 MB
    float* Spart       = (float*)(ws + (8 << 20));           // 8 MB
    unsigned short* Wt = (unsigned short*)(ws + (16 << 20)); // 4 MB
    float* E1p         = (float*)(ws + (20 << 20));
    float* E1n         = (float*)(ws + (20 << 20) + (128 << 10));
    float* E2p         = (float*)(ws + (20 << 20) + (256 << 10));
    float* E2n         = (float*)(ws + (20 << 20) + (384 << 10));
    unsigned long long* rowmask = (unsigned long long*)(ws + (20 << 20) + (512 << 10)); // 2 MB
    float* E1i         = (float*)(ws + (20 << 20) + (512 << 10) + (2 << 20)); // 256 KB
    const unsigned int* rowmask32 = (const unsigned int*)rowmask;
    // 4 bf16 partial buffers (4 MB each, lane-native layout) overlay Wh+Spart
    unsigned short* hpq = (unsigned short*)ws;               // 16 MB total

    k1_wh<<<dim3(BB * TN / 4), dim3(256), 0, stream>>>(h, ht, W, a1, a2, Wh,
                                                       E1p, E1n, E2p, E2n, E1i);
    k2_mask_stats<<<dim3(16, 64), dim3(256), 0, stream>>>(adj, E1i, E2p, E2n,
                                                          rowmask, Spart);
    k3_whn<<<dim3(64, 8), dim3(256), 0, stream>>>(Wh, Spart, Wt);
    k4_pv<<<dim3(2048), dim3(256), 0, stream>>>(rowmask32, E1p, E1n, E2p, E2n, Wt,
                                                hpq);
    k5_epi<<<dim3(2048), dim3(256), 0, stream>>>(hpq, out);
}

// Round 14
// 215.642 us; speedup vs baseline: 1.5477x; 1.5477x over previous
//
#include <hip/hip_runtime.h>
#include <hip/hip_bf16.h>
#include <math.h>

#define BB 8
#define NN 2048
#define TN 4096
#define DD 64

typedef __attribute__((ext_vector_type(8))) short short8;
typedef __attribute__((ext_vector_type(4))) float f32x4;
typedef __attribute__((ext_vector_type(4))) unsigned int u32x4;

__device__ __forceinline__ unsigned short f2bf(float f) {
    union { float f; unsigned int i; } v; v.f = f;
    unsigned int r = v.i + 0x7FFF + ((v.i >> 16) & 1);   // RNE
    return (unsigned short)(r >> 16);
}
__device__ __forceinline__ float bf2f(unsigned short u) {
    union { unsigned int i; float f; } v; v.i = ((unsigned int)u) << 16; return v.f;
}

// K1: Wh = concat(ht,h) @ W (f32); s1 = Wh@a1, s2 = Wh@a2; exp tables.
__global__ void k1_wh(const float* __restrict__ h,
                      const float* __restrict__ ht,
                      const float* __restrict__ W,
                      const float* __restrict__ a1,
                      const float* __restrict__ a2,
                      float* __restrict__ Wh,
                      float* __restrict__ E1p, float* __restrict__ E1n,
                      float* __restrict__ E2p, float* __restrict__ E2n,
                      float* __restrict__ E1i) {
    int tid = threadIdx.x;
    int w = tid >> 6, l = tid & 63;
    int rowglob = blockIdx.x * 4 + w;          // b*TN + m
    int b = rowglob >> 12;
    int m = rowglob & (TN - 1);
    const float* src = (m < NN) ? (ht + ((size_t)b * NN + m) * DD)
                                : (h  + ((size_t)b * NN + (m - NN)) * DD);
    const f32x4* src4 = reinterpret_cast<const f32x4*>(src);
    float c0 = 0.f, c1 = 0.f, c2 = 0.f, c3 = 0.f;
    #pragma unroll
    for (int k = 0; k < 16; ++k) {
        f32x4 s = src4[k];                      // wave-uniform 16B broadcast
        c0 += s[0] * W[(k * 4 + 0) * 64 + l];
        c1 += s[1] * W[(k * 4 + 1) * 64 + l];
        c2 += s[2] * W[(k * 4 + 2) * 64 + l];
        c3 += s[3] * W[(k * 4 + 3) * 64 + l];
    }
    float acc = (c0 + c1) + (c2 + c3);
    Wh[((size_t)b * TN + m) * DD + l] = acc;
    float r1 = acc * a1[l];
    float r2 = acc * a2[l];
    #pragma unroll
    for (int off = 32; off > 0; off >>= 1) {
        r1 += __shfl_xor(r1, off, 64);
        r2 += __shfl_xor(r2, off, 64);
    }
    if (l == 0) {
        size_t o = (size_t)b * TN + m;
        float pp = __expf(r1), pn = __expf(0.2f * r1);
        E1p[o] = pp;
        E1n[o] = pn;
        int sp = (b < 4) ? b       : 8 + (b - 4);
        int sn = (b < 4) ? 4 + b   : 12 + (b - 4);
        E1i[(size_t)m * 16 + sp] = pp;
        E1i[(size_t)m * 16 + sn] = pn;
        E2p[o] = __expf(r2);
        E2n[o] = __expf(0.2f * r2);
    }
}

// K2: stream ONLY the dense quadrants TL (i<2048,j<2048) and BR (i,j>=2048).
// BL is exactly 0, TR is exactly I (handled analytically in k3/k4).
// qmask[i][32] u64: bits = j within row's own half. Spart[strip32][b][j].
// grid (8 j-tiles, 32 i-strips, 2 quadrants), 256 thr.
__global__ __launch_bounds__(256) void k2_mask_stats(
    const float* __restrict__ adj,
    const float* __restrict__ E1i,
    const float* __restrict__ E2p, const float* __restrict__ E2n,
    unsigned long long* __restrict__ qmask,
    float* __restrict__ Spart) {
    int tid = threadIdx.x;
    int w = tid >> 6, l = tid & 63;
    int half = blockIdx.z;
    int jbase = half * 2048;
    int j = jbase + blockIdx.x * 256 + tid;     // global column
    int i0 = half * 2048 + blockIdx.y * 64;     // global row base
    f32x4 e2p0, e2p1, e2n0, e2n1;
    #pragma unroll
    for (int b = 0; b < 4; ++b) {
        e2p0[b] = E2p[(size_t)b * TN + j];
        e2n0[b] = E2n[(size_t)b * TN + j];
        e2p1[b] = E2p[(size_t)(b + 4) * TN + j];
        e2n1[b] = E2n[(size_t)(b + 4) * TN + j];
    }
    f32x4 acc0 = {0.f, 0.f, 0.f, 0.f}, acc1 = {0.f, 0.f, 0.f, 0.f};
    const f32x4* e1 = reinterpret_cast<const f32x4*>(E1i + (size_t)i0 * 16);
    #pragma unroll 4
    for (int ii = 0; ii < 64; ++ii) {
        float av = adj[(size_t)(i0 + ii) * TN + j];     // coalesced 256B/wave
        unsigned long long bal = __ballot(av != 0.f);
        if (l == 0)
            qmask[(size_t)(i0 + ii) * 32 + blockIdx.x * 4 + w] = bal;
        f32x4 P0 = e1[ii * 4 + 0];                      // wave-uniform loads
        f32x4 N0 = e1[ii * 4 + 1];
        f32x4 P1 = e1[ii * 4 + 2];
        f32x4 N1 = e1[ii * 4 + 3];
        f32x4 v0 = __builtin_elementwise_max(P0 * e2p0, N0 * e2n0);
        f32x4 v1 = __builtin_elementwise_max(P1 * e2p1, N1 * e2n1);
        acc0 += v0 * av;                                 // av in {0,1}: exact mask
        acc1 += v1 * av;
    }
    #pragma unroll
    for (int b = 0; b < 4; ++b) {
        Spart[((size_t)blockIdx.y * 8 + b) * TN + j]     = acc0[b];
        Spart[((size_t)blockIdx.y * 8 + b + 4) * TN + j] = acc1[b];
    }
}

// K3: S = sum(32 strips) + identity term for j>=2048; then
// Whn_t[b][d][j] = Wh[b][j][d]/S[b][j] (bf16, transposed).
__global__ __launch_bounds__(256) void k3_whn(
    const float* __restrict__ Wh,
    const float* __restrict__ Spart,
    const float* __restrict__ E1p, const float* __restrict__ E1n,
    const float* __restrict__ E2p, const float* __restrict__ E2n,
    unsigned short* __restrict__ Wt) {
    __shared__ float tile[64][65];
    __shared__ float ps[4][64];
    __shared__ float rs[64];
    int b = blockIdx.y;
    int j0 = blockIdx.x * 64;
    int tid = threadIdx.x;
    int jj = tid & 63, part = tid >> 6;
    float s = 0.f;
    #pragma unroll
    for (int k = 0; k < 8; ++k) {
        int strip = part * 8 + k;
        s += Spart[((size_t)strip * 8 + b) * TN + j0 + jj];
    }
    ps[part][jj] = s;
    __syncthreads();
    if (tid < 64) {
        float tot = ps[0][tid] + ps[1][tid] + ps[2][tid] + ps[3][tid];
        int j = j0 + tid;
        if (j >= NN) {                 // identity column term (adj TR = I)
            int i = j - NN;
            tot += fmaxf(E1p[(size_t)b * TN + i] * E2p[(size_t)b * TN + j],
                         E1n[(size_t)b * TN + i] * E2n[(size_t)b * TN + j]);
        }
        rs[tid] = 1.0f / tot;
    }
    for (int e = tid; e < 4096; e += 256) {
        int jt = e >> 6, d = e & 63;
        tile[jt][d] = Wh[((size_t)b * TN + j0 + jt) * DD + d];
    }
    __syncthreads();
    for (int e = tid; e < 512; e += 256) {
        int d = e >> 3, jg = e & 7;
        union { unsigned short u[8]; short8 s8; } pk;
        #pragma unroll
        for (int k = 0; k < 8; ++k) {
            int jt = jg * 8 + k;
            pk.u[k] = f2bf(tile[jt][d] * rs[jt]);
        }
        *reinterpret_cast<short8*>(Wt + ((size_t)b * DD + d) * TN + j0 + jg * 8) = pk.s8;
    }
}

// K4: each i-row only needs its own 2048-j half (BL=0, TR=I analytic).
// js=4 quarters of 512 j -> jt loop 4. grid 2048 = 8 blocks/CU. LDS B-tile
// (128j x 64d, stride 140), 2-barrier jt loop + register prefetch (r12 proven).
// Diagonal I-term added in f32 to js==0 blocks of the upper half.
__global__ __launch_bounds__(256) void k4_pv(
    const unsigned int* __restrict__ qmask32,
    const float* __restrict__ E1p, const float* __restrict__ E1n,
    const float* __restrict__ E2p, const float* __restrict__ E2n,
    const unsigned short* __restrict__ Wt,
    unsigned short* __restrict__ hpq) {
    __shared__ unsigned short wt_s[64 * 140];
    int bx = blockIdx.x;
    int b  = bx & 7;                 // XCD round-robin
    int js = (bx >> 3) & 3;
    int it = bx >> 5;                // i-tile index 0..63
    int i0 = it * 64;
    int half = (it >= 32);           // 0: i<2048 -> j in [0,2048); 1: j in [2048,4096)
    int tid = threadIdx.x;
    int w = tid >> 6, l = tid & 63;
    int m = l & 15, q = l >> 4;
    int irow = i0 + w * 16 + m;
    float e1p_v = E1p[(size_t)b * TN + irow];
    float e1n_v = E1n[(size_t)b * TN + irow];
    const float* e2pb = E2p + (size_t)b * TN;
    const float* e2nb = E2n + (size_t)b * TN;
    const unsigned short* wtb = Wt + (size_t)b * DD * TN;
    const unsigned int* mrow = qmask32 + (size_t)irow * 64;   // own-half bits

    int r0 = tid >> 4, c0 = tid & 15;
    const int jbase = half * 2048 + js * 512;   // global j base
    const int jloc0 = js * 512;                 // local (in-half) bit base

    f32x4 acc[4];
    #pragma unroll
    for (int dt = 0; dt < 4; ++dt) acc[dt] = (f32x4){0.f, 0.f, 0.f, 0.f};

    // prefetch tile jt=0
    short8 g[4];
    #pragma unroll
    for (int k = 0; k < 4; ++k)
        g[k] = *reinterpret_cast<const short8*>(
            wtb + (size_t)(r0 + 16 * k) * TN + jbase + c0 * 8);

    for (int jt = 0; jt < 4; ++jt) {
        int j0 = jbase + jt * 128;
        __syncthreads();                                  // prior reads done
        #pragma unroll
        for (int k = 0; k < 4; ++k)
            *reinterpret_cast<short8*>(&wt_s[(r0 + 16 * k) * 140 + c0 * 8]) = g[k];
        if (jt < 3) {                                     // prefetch next tile
            #pragma unroll
            for (int k = 0; k < 4; ++k)
                g[k] = *reinterpret_cast<const short8*>(
                    wtb + (size_t)(r0 + 16 * k) * TN + j0 + 128 + c0 * 8);
        }
        u32x4 m4 = *reinterpret_cast<const u32x4*>(mrow + ((jloc0 + jt * 128) >> 5));
        __syncthreads();                                  // tile visible

        #pragma unroll
        for (int t = 0; t < 4; ++t) {
            int jb = j0 + t * 32 + q * 8;
            unsigned int bytev = (m4[t] >> (q * 8)) & 0xFFu;
            f32x4 p20 = *reinterpret_cast<const f32x4*>(e2pb + jb);
            f32x4 p21 = *reinterpret_cast<const f32x4*>(e2pb + jb + 4);
            f32x4 n20 = *reinterpret_cast<const f32x4*>(e2nb + jb);
            f32x4 n21 = *reinterpret_cast<const f32x4*>(e2nb + jb + 4);
            f32x4 v0 = __builtin_elementwise_max(p20 * e1p_v, n20 * e1n_v);
            f32x4 v1 = __builtin_elementwise_max(p21 * e1p_v, n21 * e1n_v);
            union { f32x4 f; u32x4 u; } uv0, uv1;
            uv0.f = v0; uv1.f = v1;
            u32x4 mk0, mk1;
            #pragma unroll
            for (int c = 0; c < 4; ++c) {
                mk0[c] = (unsigned int)((int)(bytev << (31 - c)) >> 31);
                mk1[c] = (unsigned int)((int)(bytev << (27 - c)) >> 31);
            }
            uv0.u &= mk0; uv1.u &= mk1;
            union { unsigned int u[4]; short8 s8; } af;
            __hip_bfloat162 hb0 = __float22bfloat162_rn(make_float2(uv0.f[0], uv0.f[1]));
            __hip_bfloat162 hb1 = __float22bfloat162_rn(make_float2(uv0.f[2], uv0.f[3]));
            __hip_bfloat162 hb2 = __float22bfloat162_rn(make_float2(uv1.f[0], uv1.f[1]));
            __hip_bfloat162 hb3 = __float22bfloat162_rn(make_float2(uv1.f[2], uv1.f[3]));
            af.u[0] = *reinterpret_cast<unsigned int*>(&hb0);
            af.u[1] = *reinterpret_cast<unsigned int*>(&hb1);
            af.u[2] = *reinterpret_cast<unsigned int*>(&hb2);
            af.u[3] = *reinterpret_cast<unsigned int*>(&hb3);
            #pragma unroll
            for (int dt = 0; dt < 4; ++dt) {
                short8 bf = *reinterpret_cast<const short8*>(
                    &wt_s[(dt * 16 + m) * 140 + t * 32 + q * 8]);
                acc[dt] = __builtin_amdgcn_mfma_f32_16x16x32_bf16(af.s8, bf, acc[dt], 0, 0, 0);
            }
        }
    }

    // Diagonal identity term (adj TR = I): rows i<2048 get + E(i)*Whn[i+2048].
    // Added once, in f32, by the js==0 block of the upper half.
    int gbase = i0 + w * 16 + q * 4;
    if (half == 0 && js == 0) {
        #pragma unroll
        for (int r = 0; r < 4; ++r) {
            int gg = gbase + r;
            float ed = fmaxf(E1p[(size_t)b * TN + gg] * e2pb[gg + NN],
                             E1n[(size_t)b * TN + gg] * e2nb[gg + NN]);
            #pragma unroll
            for (int dt = 0; dt < 4; ++dt) {
                int d = dt * 16 + m;
                acc[dt][r] += ed * bf2f(wtb[(size_t)d * TN + gg + NN]);
            }
        }
    }

    // Epilogue: lane-native layout. element (js,b,it,w,lane,k) with k=dt*4+r.
    union { unsigned int u[8]; u32x4 v[2]; } pk;
    #pragma unroll
    for (int dt = 0; dt < 4; ++dt) {
        __hip_bfloat162 p0 = __float22bfloat162_rn(make_float2(acc[dt][0], acc[dt][1]));
        __hip_bfloat162 p1 = __float22bfloat162_rn(make_float2(acc[dt][2], acc[dt][3]));
        pk.u[dt * 2 + 0] = *reinterpret_cast<unsigned int*>(&p0);
        pk.u[dt * 2 + 1] = *reinterpret_cast<unsigned int*>(&p1);
    }
    unsigned short* hp = hpq +
        (((((size_t)js * 8 + b) * 64 + it) * 4 + w) * 64 + l) * 16;
    *reinterpret_cast<u32x4*>(hp)     = pk.v[0];
    *reinterpret_cast<u32x4*>(hp + 8) = pk.v[1];
}

// K5: out = elu(sum_js hp[js]) with concat remap + layout unpermute; f32 store.
__global__ void k5_epi(const unsigned short* __restrict__ hpq,
                       float* __restrict__ out) {
    int t = blockIdx.x * 256 + threadIdx.x;       // < 524288
    int d4 = t & 31;
    int n = (t >> 5) & 2047;
    int b = t >> 16;
    int g, sd;
    if (d4 < 16) { g = n;        sd = d4 * 4; }
    else         { g = n + NN;   sd = (d4 - 16) * 4; }
    int it = g >> 6, w = (g >> 4) & 3, q = (g >> 2) & 3, r = g & 3;
    int dt = sd >> 4, m0 = sd & 15;
    const size_t JSTR = (size_t)8 * 64 * 4 * 64 * 16;   // 2,097,152 ushorts / js
    size_t base = ((((size_t)b * 64 + it) * 4 + w) * 64 + q * 16) * 16 + dt * 4 + r;
    f32x4 s = {0.f, 0.f, 0.f, 0.f};
    #pragma unroll
    for (int js = 0; js < 4; ++js) {
        const unsigned short* p = hpq + js * JSTR + base;
        #pragma unroll
        for (int c = 0; c < 4; ++c) s[c] += bf2f(p[(size_t)(m0 + c) * 16]);
    }
    f32x4 rr;
    #pragma unroll
    for (int c = 0; c < 4; ++c) rr[c] = (s[c] > 0.f) ? s[c] : expm1f(s[c]);
    *reinterpret_cast<f32x4*>(out + ((size_t)b * NN + n) * 128 + d4 * 4) = rr;
}

extern "C" void kernel_launch(void* const* d_in, const int* in_sizes, int n_in,
                              void* d_out, int out_size, void* d_ws, size_t ws_size,
                              hipStream_t stream) {
    const float* h   = (const float*)d_in[0];
    const float* ht  = (const float*)d_in[1];
    const float* W   = (const float*)d_in[2];
    const float* a1  = (const float*)d_in[3];
    const float* a2  = (const float*)d_in[4];
    const float* adj = (const float*)d_in[5];
    float* out = (float*)d_out;

    char* ws = (char*)d_ws;
    float* Wh          = (float*)(ws);                       // 8 MB
    float* Spart       = (float*)(ws + (8 << 20));           // 4 MB used (8 reserved)
    unsigned short* Wt = (unsigned short*)(ws + (16 << 20)); // 4 MB
    float* E1p         = (float*)(ws + (20 << 20));
    float* E1n         = (float*)(ws + (20 << 20) + (128 << 10));
    float* E2p         = (float*)(ws + (20 << 20) + (256 << 10));
    float* E2n         = (float*)(ws + (20 << 20) + (384 << 10));
    unsigned long long* qmask = (unsigned long long*)(ws + (20 << 20) + (512 << 10)); // 1 MB
    float* E1i         = (float*)(ws + (20 << 20) + (512 << 10) + (2 << 20)); // 256 KB
    const unsigned int* qmask32 = (const unsigned int*)qmask;
    // 4 bf16 partial buffers (4 MB each, lane-native layout) overlay Wh+Spart
    unsigned short* hpq = (unsigned short*)ws;               // 16 MB total

    k1_wh<<<dim3(BB * TN / 4), dim3(256), 0, stream>>>(h, ht, W, a1, a2, Wh,
                                                       E1p, E1n, E2p, E2n, E1i);
    k2_mask_stats<<<dim3(8, 32, 2), dim3(256), 0, stream>>>(adj, E1i, E2p, E2n,
                                                            qmask, Spart);
    k3_whn<<<dim3(64, 8), dim3(256), 0, stream>>>(Wh, Spart, E1p, E1n, E2p, E2n, Wt);
    k4_pv<<<dim3(2048), dim3(256), 0, stream>>>(qmask32, E1p, E1n, E2p, E2n, Wt,
                                                hpq);
    k5_epi<<<dim3(2048), dim3(256), 0, stream>>>(hpq, out);
}

// Round 15
// 195.744 us; speedup vs baseline: 1.7050x; 1.1017x over previous
//
#include <hip/hip_runtime.h>
#include <hip/hip_bf16.h>
#include <math.h>

#define BB 8
#define NN 2048
#define TN 4096
#define DD 64

typedef __attribute__((ext_vector_type(8))) short short8;
typedef __attribute__((ext_vector_type(4))) float f32x4;
typedef __attribute__((ext_vector_type(4))) unsigned int u32x4;

__device__ __forceinline__ unsigned short f2bf(float f) {
    union { float f; unsigned int i; } v; v.f = f;
    unsigned int r = v.i + 0x7FFF + ((v.i >> 16) & 1);   // RNE
    return (unsigned short)(r >> 16);
}
__device__ __forceinline__ float bf2f(unsigned short u) {
    union { unsigned int i; float f; } v; v.i = ((unsigned int)u) << 16; return v.f;
}

// K1: Wh = concat(ht,h) @ W (f32); s1 = Wh@a1, s2 = Wh@a2; exp tables.
__global__ void k1_wh(const float* __restrict__ h,
                      const float* __restrict__ ht,
                      const float* __restrict__ W,
                      const float* __restrict__ a1,
                      const float* __restrict__ a2,
                      float* __restrict__ Wh,
                      float* __restrict__ E1p, float* __restrict__ E1n,
                      float* __restrict__ E2p, float* __restrict__ E2n,
                      float* __restrict__ E1i) {
    int tid = threadIdx.x;
    int w = tid >> 6, l = tid & 63;
    int rowglob = blockIdx.x * 4 + w;          // b*TN + m
    int b = rowglob >> 12;
    int m = rowglob & (TN - 1);
    const float* src = (m < NN) ? (ht + ((size_t)b * NN + m) * DD)
                                : (h  + ((size_t)b * NN + (m - NN)) * DD);
    const f32x4* src4 = reinterpret_cast<const f32x4*>(src);
    float c0 = 0.f, c1 = 0.f, c2 = 0.f, c3 = 0.f;
    #pragma unroll
    for (int k = 0; k < 16; ++k) {
        f32x4 s = src4[k];                      // wave-uniform 16B broadcast
        c0 += s[0] * W[(k * 4 + 0) * 64 + l];
        c1 += s[1] * W[(k * 4 + 1) * 64 + l];
        c2 += s[2] * W[(k * 4 + 2) * 64 + l];
        c3 += s[3] * W[(k * 4 + 3) * 64 + l];
    }
    float acc = (c0 + c1) + (c2 + c3);
    Wh[((size_t)b * TN + m) * DD + l] = acc;
    float r1 = acc * a1[l];
    float r2 = acc * a2[l];
    #pragma unroll
    for (int off = 32; off > 0; off >>= 1) {
        r1 += __shfl_xor(r1, off, 64);
        r2 += __shfl_xor(r2, off, 64);
    }
    if (l == 0) {
        size_t o = (size_t)b * TN + m;
        float pp = __expf(r1), pn = __expf(0.2f * r1);
        E1p[o] = pp;
        E1n[o] = pn;
        int sp = (b < 4) ? b       : 8 + (b - 4);
        int sn = (b < 4) ? 4 + b   : 12 + (b - 4);
        E1i[(size_t)m * 16 + sp] = pp;
        E1i[(size_t)m * 16 + sn] = pn;
        E2p[o] = __expf(r2);
        E2n[o] = __expf(0.2f * r2);
    }
}

// K2: stream ONLY dense quadrants TL/BR. 32-row strips, grid (8,64,2)=1024
// blocks (4/CU). Loads batched 8-deep BEFORE ballots (each __ballot is a
// load-dependent wave sync -> batching keeps 8 loads in flight).
__global__ __launch_bounds__(256) void k2_mask_stats(
    const float* __restrict__ adj,
    const float* __restrict__ E1i,
    const float* __restrict__ E2p, const float* __restrict__ E2n,
    unsigned long long* __restrict__ qmask,
    float* __restrict__ Spart) {
    int tid = threadIdx.x;
    int w = tid >> 6, l = tid & 63;
    int half = blockIdx.z;
    int j = half * 2048 + blockIdx.x * 256 + tid;   // global column
    int i0 = half * 2048 + blockIdx.y * 32;         // global row base (32-strip)
    f32x4 e2p0, e2p1, e2n0, e2n1;
    #pragma unroll
    for (int b = 0; b < 4; ++b) {
        e2p0[b] = E2p[(size_t)b * TN + j];
        e2n0[b] = E2n[(size_t)b * TN + j];
        e2p1[b] = E2p[(size_t)(b + 4) * TN + j];
        e2n1[b] = E2n[(size_t)(b + 4) * TN + j];
    }
    f32x4 acc0 = {0.f, 0.f, 0.f, 0.f}, acc1 = {0.f, 0.f, 0.f, 0.f};
    const f32x4* e1 = reinterpret_cast<const f32x4*>(E1i + (size_t)i0 * 16);
    for (int it8 = 0; it8 < 4; ++it8) {
        float avv[8];
        #pragma unroll
        for (int k = 0; k < 8; ++k)                       // 8 loads in flight
            avv[k] = adj[(size_t)(i0 + it8 * 8 + k) * TN + j];
        #pragma unroll
        for (int k = 0; k < 8; ++k) {
            int ii = it8 * 8 + k;
            unsigned long long bal = __ballot(avv[k] != 0.f);
            if (l == 0)
                qmask[(size_t)(i0 + ii) * 32 + blockIdx.x * 4 + w] = bal;
            f32x4 P0 = e1[ii * 4 + 0];                    // wave-uniform loads
            f32x4 N0 = e1[ii * 4 + 1];
            f32x4 P1 = e1[ii * 4 + 2];
            f32x4 N1 = e1[ii * 4 + 3];
            f32x4 v0 = __builtin_elementwise_max(P0 * e2p0, N0 * e2n0);
            f32x4 v1 = __builtin_elementwise_max(P1 * e2p1, N1 * e2n1);
            acc0 += v0 * avv[k];                          // av in {0,1}: exact mask
            acc1 += v1 * avv[k];
        }
    }
    #pragma unroll
    for (int b = 0; b < 4; ++b) {
        Spart[((size_t)blockIdx.y * 8 + b) * TN + j]     = acc0[b];
        Spart[((size_t)blockIdx.y * 8 + b + 4) * TN + j] = acc1[b];
    }
}

// K3: S = sum(64 strips) + identity term for j>=2048; then
// Whn_t[b][d][j] = Wh[b][j][d]/S[b][j] (bf16, transposed).
__global__ __launch_bounds__(256) void k3_whn(
    const float* __restrict__ Wh,
    const float* __restrict__ Spart,
    const float* __restrict__ E1p, const float* __restrict__ E1n,
    const float* __restrict__ E2p, const float* __restrict__ E2n,
    unsigned short* __restrict__ Wt) {
    __shared__ float tile[64][65];
    __shared__ float ps[4][64];
    __shared__ float rs[64];
    int b = blockIdx.y;
    int j0 = blockIdx.x * 64;
    int tid = threadIdx.x;
    int jj = tid & 63, part = tid >> 6;
    float s = 0.f;
    #pragma unroll
    for (int k = 0; k < 16; ++k) {
        int strip = part * 16 + k;
        s += Spart[((size_t)strip * 8 + b) * TN + j0 + jj];
    }
    ps[part][jj] = s;
    __syncthreads();
    if (tid < 64) {
        float tot = ps[0][tid] + ps[1][tid] + ps[2][tid] + ps[3][tid];
        int j = j0 + tid;
        if (j >= NN) {                 // identity column term (adj TR = I)
            int i = j - NN;
            tot += fmaxf(E1p[(size_t)b * TN + i] * E2p[(size_t)b * TN + j],
                         E1n[(size_t)b * TN + i] * E2n[(size_t)b * TN + j]);
        }
        rs[tid] = 1.0f / tot;
    }
    for (int e = tid; e < 4096; e += 256) {
        int jt = e >> 6, d = e & 63;
        tile[jt][d] = Wh[((size_t)b * TN + j0 + jt) * DD + d];
    }
    __syncthreads();
    for (int e = tid; e < 512; e += 256) {
        int d = e >> 3, jg = e & 7;
        union { unsigned short u[8]; short8 s8; } pk;
        #pragma unroll
        for (int k = 0; k < 8; ++k) {
            int jt = jg * 8 + k;
            pk.u[k] = f2bf(tile[jt][d] * rs[jt]);
        }
        *reinterpret_cast<short8*>(Wt + ((size_t)b * DD + d) * TN + j0 + jg * 8) = pk.s8;
    }
}

// K4: each i-row only needs its own 2048-j half (BL=0, TR=I analytic).
// js=4 quarters of 512 j -> jt loop 4. grid 2048 = 8 blocks/CU. LDS B-tile
// (128j x 64d, stride 140), 2-barrier jt loop + register prefetch.
// Diagonal I-term added in f32 by js==0 blocks of the upper half.
__global__ __launch_bounds__(256) void k4_pv(
    const unsigned int* __restrict__ qmask32,
    const float* __restrict__ E1p, const float* __restrict__ E1n,
    const float* __restrict__ E2p, const float* __restrict__ E2n,
    const unsigned short* __restrict__ Wt,
    unsigned short* __restrict__ hpq) {
    __shared__ unsigned short wt_s[64 * 140];
    int bx = blockIdx.x;
    int b  = bx & 7;                 // XCD round-robin
    int js = (bx >> 3) & 3;
    int it = bx >> 5;                // i-tile index 0..63
    int i0 = it * 64;
    int half = (it >= 32);           // 0: i<2048 -> j in [0,2048); 1: j in [2048,4096)
    int tid = threadIdx.x;
    int w = tid >> 6, l = tid & 63;
    int m = l & 15, q = l >> 4;
    int irow = i0 + w * 16 + m;
    float e1p_v = E1p[(size_t)b * TN + irow];
    float e1n_v = E1n[(size_t)b * TN + irow];
    const float* e2pb = E2p + (size_t)b * TN;
    const float* e2nb = E2n + (size_t)b * TN;
    const unsigned short* wtb = Wt + (size_t)b * DD * TN;
    const unsigned int* mrow = qmask32 + (size_t)irow * 64;   // own-half bits

    int r0 = tid >> 4, c0 = tid & 15;
    const int jbase = half * 2048 + js * 512;   // global j base
    const int jloc0 = js * 512;                 // local (in-half) bit base

    f32x4 acc[4];
    #pragma unroll
    for (int dt = 0; dt < 4; ++dt) acc[dt] = (f32x4){0.f, 0.f, 0.f, 0.f};

    // prefetch tile jt=0
    short8 g[4];
    #pragma unroll
    for (int k = 0; k < 4; ++k)
        g[k] = *reinterpret_cast<const short8*>(
            wtb + (size_t)(r0 + 16 * k) * TN + jbase + c0 * 8);

    for (int jt = 0; jt < 4; ++jt) {
        int j0 = jbase + jt * 128;
        __syncthreads();                                  // prior reads done
        #pragma unroll
        for (int k = 0; k < 4; ++k)
            *reinterpret_cast<short8*>(&wt_s[(r0 + 16 * k) * 140 + c0 * 8]) = g[k];
        if (jt < 3) {                                     // prefetch next tile
            #pragma unroll
            for (int k = 0; k < 4; ++k)
                g[k] = *reinterpret_cast<const short8*>(
                    wtb + (size_t)(r0 + 16 * k) * TN + j0 + 128 + c0 * 8);
        }
        u32x4 m4 = *reinterpret_cast<const u32x4*>(mrow + ((jloc0 + jt * 128) >> 5));
        __syncthreads();                                  // tile visible

        #pragma unroll
        for (int t = 0; t < 4; ++t) {
            int jb = j0 + t * 32 + q * 8;
            unsigned int bytev = (m4[t] >> (q * 8)) & 0xFFu;
            f32x4 p20 = *reinterpret_cast<const f32x4*>(e2pb + jb);
            f32x4 p21 = *reinterpret_cast<const f32x4*>(e2pb + jb + 4);
            f32x4 n20 = *reinterpret_cast<const f32x4*>(e2nb + jb);
            f32x4 n21 = *reinterpret_cast<const f32x4*>(e2nb + jb + 4);
            f32x4 v0 = __builtin_elementwise_max(p20 * e1p_v, n20 * e1n_v);
            f32x4 v1 = __builtin_elementwise_max(p21 * e1p_v, n21 * e1n_v);
            union { f32x4 f; u32x4 u; } uv0, uv1;
            uv0.f = v0; uv1.f = v1;
            u32x4 mk0, mk1;
            #pragma unroll
            for (int c = 0; c < 4; ++c) {
                mk0[c] = (unsigned int)((int)(bytev << (31 - c)) >> 31);
                mk1[c] = (unsigned int)((int)(bytev << (27 - c)) >> 31);
            }
            uv0.u &= mk0; uv1.u &= mk1;
            union { unsigned int u[4]; short8 s8; } af;
            __hip_bfloat162 hb0 = __float22bfloat162_rn(make_float2(uv0.f[0], uv0.f[1]));
            __hip_bfloat162 hb1 = __float22bfloat162_rn(make_float2(uv0.f[2], uv0.f[3]));
            __hip_bfloat162 hb2 = __float22bfloat162_rn(make_float2(uv1.f[0], uv1.f[1]));
            __hip_bfloat162 hb3 = __float22bfloat162_rn(make_float2(uv1.f[2], uv1.f[3]));
            af.u[0] = *reinterpret_cast<unsigned int*>(&hb0);
            af.u[1] = *reinterpret_cast<unsigned int*>(&hb1);
            af.u[2] = *reinterpret_cast<unsigned int*>(&hb2);
            af.u[3] = *reinterpret_cast<unsigned int*>(&hb3);
            #pragma unroll
            for (int dt = 0; dt < 4; ++dt) {
                short8 bf = *reinterpret_cast<const short8*>(
                    &wt_s[(dt * 16 + m) * 140 + t * 32 + q * 8]);
                acc[dt] = __builtin_amdgcn_mfma_f32_16x16x32_bf16(af.s8, bf, acc[dt], 0, 0, 0);
            }
        }
    }

    // Diagonal identity term (adj TR = I): rows i<2048 get + E(i)*Whn[i+2048].
    int gbase = i0 + w * 16 + q * 4;
    if (half == 0 && js == 0) {
        #pragma unroll
        for (int r = 0; r < 4; ++r) {
            int gg = gbase + r;
            float ed = fmaxf(E1p[(size_t)b * TN + gg] * e2pb[gg + NN],
                             E1n[(size_t)b * TN + gg] * e2nb[gg + NN]);
            #pragma unroll
            for (int dt = 0; dt < 4; ++dt) {
                int d = dt * 16 + m;
                acc[dt][r] += ed * bf2f(wtb[(size_t)d * TN + gg + NN]);
            }
        }
    }

    // Epilogue: lane-native layout. element (js,b,it,w,lane,k) with k=dt*4+r.
    union { unsigned int u[8]; u32x4 v[2]; } pk;
    #pragma unroll
    for (int dt = 0; dt < 4; ++dt) {
        __hip_bfloat162 p0 = __float22bfloat162_rn(make_float2(acc[dt][0], acc[dt][1]));
        __hip_bfloat162 p1 = __float22bfloat162_rn(make_float2(acc[dt][2], acc[dt][3]));
        pk.u[dt * 2 + 0] = *reinterpret_cast<unsigned int*>(&p0);
        pk.u[dt * 2 + 1] = *reinterpret_cast<unsigned int*>(&p1);
    }
    unsigned short* hp = hpq +
        (((((size_t)js * 8 + b) * 64 + it) * 4 + w) * 64 + l) * 16;
    *reinterpret_cast<u32x4*>(hp)     = pk.v[0];
    *reinterpret_cast<u32x4*>(hp + 8) = pk.v[1];
}

// K5: out = elu(sum_js hp[js]) with concat remap + layout unpermute; f32 store.
__global__ void k5_epi(const unsigned short* __restrict__ hpq,
                       float* __restrict__ out) {
    int t = blockIdx.x * 256 + threadIdx.x;       // < 524288
    int d4 = t & 31;
    int n = (t >> 5) & 2047;
    int b = t >> 16;
    int g, sd;
    if (d4 < 16) { g = n;        sd = d4 * 4; }
    else         { g = n + NN;   sd = (d4 - 16) * 4; }
    int it = g >> 6, w = (g >> 4) & 3, q = (g >> 2) & 3, r = g & 3;
    int dt = sd >> 4, m0 = sd & 15;
    const size_t JSTR = (size_t)8 * 64 * 4 * 64 * 16;   // 2,097,152 ushorts / js
    size_t base = ((((size_t)b * 64 + it) * 4 + w) * 64 + q * 16) * 16 + dt * 4 + r;
    f32x4 s = {0.f, 0.f, 0.f, 0.f};
    #pragma unroll
    for (int js = 0; js < 4; ++js) {
        const unsigned short* p = hpq + js * JSTR + base;
        #pragma unroll
        for (int c = 0; c < 4; ++c) s[c] += bf2f(p[(size_t)(m0 + c) * 16]);
    }
    f32x4 rr;
    #pragma unroll
    for (int c = 0; c < 4; ++c) rr[c] = (s[c] > 0.f) ? s[c] : expm1f(s[c]);
    *reinterpret_cast<f32x4*>(out + ((size_t)b * NN + n) * 128 + d4 * 4) = rr;
}

extern "C" void kernel_launch(void* const* d_in, const int* in_sizes, int n_in,
                              void* d_out, int out_size, void* d_ws, size_t ws_size,
                              hipStream_t stream) {
    const float* h   = (const float*)d_in[0];
    const float* ht  = (const float*)d_in[1];
    const float* W   = (const float*)d_in[2];
    const float* a1  = (const float*)d_in[3];
    const float* a2  = (const float*)d_in[4];
    const float* adj = (const float*)d_in[5];
    float* out = (float*)d_out;

    char* ws = (char*)d_ws;
    float* Wh          = (float*)(ws);                       // 8 MB
    float* Spart       = (float*)(ws + (8 << 20));           // 8 MB (64 strips)
    unsigned short* Wt = (unsigned short*)(ws + (16 << 20)); // 4 MB
    float* E1p         = (float*)(ws + (20 << 20));
    float* E1n         = (float*)(ws + (20 << 20) + (128 << 10));
    float* E2p         = (float*)(ws + (20 << 20) + (256 << 10));
    float* E2n         = (float*)(ws + (20 << 20) + (384 << 10));
    unsigned long long* qmask = (unsigned long long*)(ws + (20 << 20) + (512 << 10)); // 1 MB
    float* E1i         = (float*)(ws + (20 << 20) + (512 << 10) + (2 << 20)); // 256 KB
    const unsigned int* qmask32 = (const unsigned int*)qmask;
    // 4 bf16 partial buffers (4 MB each, lane-native layout) overlay Wh+Spart
    unsigned short* hpq = (unsigned short*)ws;               // 16 MB total

    k1_wh<<<dim3(BB * TN / 4), dim3(256), 0, stream>>>(h, ht, W, a1, a2, Wh,
                                                       E1p, E1n, E2p, E2n, E1i);
    k2_mask_stats<<<dim3(8, 64, 2), dim3(256), 0, stream>>>(adj, E1i, E2p, E2n,
                                                            qmask, Spart);
    k3_whn<<<dim3(64, 8), dim3(256), 0, stream>>>(Wh, Spart, E1p, E1n, E2p, E2n, Wt);
    k4_pv<<<dim3(2048), dim3(256), 0, stream>>>(qmask32, E1p, E1n, E2p, E2n, Wt,
                                                hpq);
    k5_epi<<<dim3(2048), dim3(256), 0, stream>>>(hpq, out);
}